// Round 6
// baseline (318.920 us; speedup 1.0000x reference)
//
#include <hip/hip_runtime.h>

typedef float f32x4 __attribute__((ext_vector_type(4)));
typedef float f32x16 __attribute__((ext_vector_type(16)));
typedef __bf16 bf16x8 __attribute__((ext_vector_type(8)));

__device__ __forceinline__ unsigned short f2bf(float f) {
  unsigned int u = __float_as_uint(f);
  u = (u + 0x7FFFu + ((u >> 16) & 1u)) >> 16;
  return (unsigned short)u;
}
__device__ __forceinline__ float bf2f(unsigned short u) {
  return __uint_as_float((unsigned int)u << 16);
}

__device__ __forceinline__ f32x4 mfma16(bf16x8 a, bf16x8 b, f32x4 c) {
  return __builtin_amdgcn_mfma_f32_16x16x32_bf16(a, b, c, 0, 0, 0);
}
__device__ __forceinline__ f32x16 mfma32(bf16x8 a, bf16x8 b, f32x16 c) {
  return __builtin_amdgcn_mfma_f32_32x32x16_bf16(a, b, c, 0, 0, 0);
}

// packed f32->bf16 pair (RNE), lo = a, hi = b
__device__ __forceinline__ unsigned int cvtpk_bf16(float a, float b) {
  unsigned int r;
  asm("v_cvt_pk_bf16_f32 %0, %1, %2" : "=v"(r) : "v"(a), "v"(b));
  return r;
}
// swap upper 32 lanes of a with lower 32 lanes of b (both outputs used)
__device__ __forceinline__ void pl32swap(unsigned int& a, unsigned int& b) {
  asm("v_permlane32_swap_b32 %0, %1" : "+v"(a), "+v"(b));
}

__device__ __forceinline__ void load8_bf16(const unsigned short* p, unsigned short* d) {
  *(uint4*)d = *(const uint4*)p;
}
__device__ __forceinline__ void load8_bf16(const float* p, unsigned short* d) {
  float4 a = *(const float4*)p;
  float4 b = *(const float4*)(p + 4);
  __align__(16) unsigned short t[8] = {f2bf(a.x), f2bf(a.y), f2bf(a.z), f2bf(a.w),
                                       f2bf(b.x), f2bf(b.y), f2bf(b.z), f2bf(b.w)};
  *(uint4*)d = *(uint4*)t;
}

// Async global->LDS 16B DMA. LDS dest must be wave-uniform base + lane*16.
__device__ __forceinline__ void gload_lds16(const unsigned short* g, unsigned short* l) {
  __builtin_amdgcn_global_load_lds(
      (const __attribute__((address_space(1))) void*)g,
      (__attribute__((address_space(3))) void*)l, 16, 0, 0);
}

__device__ __forceinline__ void drain_barrier() {
  asm volatile("s_waitcnt vmcnt(0)" ::: "memory");
  __builtin_amdgcn_sched_barrier(0);
  __builtin_amdgcn_s_barrier();
  __builtin_amdgcn_sched_barrier(0);
}

// fp32 -> bf16, 8 elems/thread.
__global__ __launch_bounds__(256) void convert_gen(const float* __restrict__ src,
                                                   unsigned short* __restrict__ dst) {
  int idx = (blockIdx.x * 256 + threadIdx.x) * 8;
  __align__(16) unsigned short t[8];
  load8_bf16(src + idx, t);
  *(uint4*)(dst + idx) = *(uint4*)t;
}

// W1|W2|W3 (each 1M fp32) -> contiguous bf16. 1536 blocks.
__global__ __launch_bounds__(256) void convert_w3(const float* __restrict__ W1,
                                                  const float* __restrict__ W2,
                                                  const float* __restrict__ W3,
                                                  unsigned short* __restrict__ dst) {
  int i = blockIdx.x;
  int sel = i >> 9;
  const float* src = (sel == 0) ? W1 : (sel == 1) ? W2 : W3;
  int off = (i & 511) * 2048 + threadIdx.x * 8;
  __align__(16) unsigned short t[8];
  load8_bf16(src + off, t);
  *(uint4*)(dst + sel * 1048576 + off) = *(uint4*)t;
}

// Fused QKV projection, all-bf16. 3-buffer LDS pipeline (2-deep prefetch):
// issue stage t+2 at top of step t, COUNTED s_waitcnt vmcnt(4) at bottom
// (queue never drains in steady state; each DMA group gets ~2 compute phases
// of latency budget). Per-thread src/dst addresses hoisted out of the K-loop.
__global__ __launch_bounds__(256) void gemm_qkv(const unsigned short* __restrict__ A,
                                                const unsigned short* __restrict__ WB,
                                                unsigned short* __restrict__ q,
                                                unsigned short* __restrict__ k,
                                                unsigned short* __restrict__ v) {
  __shared__ __align__(16) unsigned short As[3][128][32];
  __shared__ __align__(16) unsigned short Bs[3][128][32];
  const int t = threadIdx.x;
  const int lane = t & 63;
  const int wid = t >> 6;
  const int quad = lane >> 4;
  const int l16 = lane & 15;
  const int wm = (wid >> 1) << 6;
  const int wn = (wid & 1) << 6;
  const int sel = blockIdx.x >> 3;
  const int nb = (blockIdx.x & 7) << 7;
  const int mbase = blockIdx.y * 128;
  const unsigned short* Bt = WB + sel * 1048576;
  unsigned short* C = (sel == 0) ? q : (sel == 1) ? k : v;

  // per-thread loop-invariant staging addresses (row/col fixed per thread;
  // LDS dest for chunk c is linear elem offset c*8 within the buffer)
  const int c0 = t, c1 = t + 256;
  const unsigned short* aSrc0 = A + (size_t)(mbase + (c0 >> 2)) * 1024 + ((c0 & 3) << 3);
  const unsigned short* aSrc1 = A + (size_t)(mbase + (c1 >> 2)) * 1024 + ((c1 & 3) << 3);
  const unsigned short* bSrc0 = Bt + (size_t)(nb + (c0 >> 2)) * 1024 + ((c0 & 3) << 3);
  const unsigned short* bSrc1 = Bt + (size_t)(nb + (c1 >> 2)) * 1024 + ((c1 & 3) << 3);
  unsigned short* aDst0 = &As[0][0][0] + c0 * 8;
  unsigned short* aDst1 = &As[0][0][0] + c1 * 8;
  unsigned short* bDst0 = &Bs[0][0][0] + c0 * 8;
  unsigned short* bDst1 = &Bs[0][0][0] + c1 * 8;

  auto stage = [&](int k0, int p) {
    const int po = p * 4096;  // elems per buffer (8192 B)
    gload_lds16(aSrc0 + k0, aDst0 + po);
    gload_lds16(aSrc1 + k0, aDst1 + po);
    gload_lds16(bSrc0 + k0, bDst0 + po);
    gload_lds16(bSrc1 + k0, bDst1 + po);
  };

  f32x4 acc[4][4] = {};

  stage(0, 0);
  stage(32, 1);
  asm volatile("s_waitcnt vmcnt(4)" ::: "memory");  // stage 0 landed
  __builtin_amdgcn_sched_barrier(0);
  __builtin_amdgcn_s_barrier();
  __builtin_amdgcn_sched_barrier(0);

  int p = 0;
  for (int k0 = 0; k0 < 1024; k0 += 32) {
    if (k0 + 64 < 1024) stage(k0 + 64, p == 0 ? 2 : p - 1);  // (p+2)%3
    bf16x8 af[4], bfr[4];
#pragma unroll
    for (int mt = 0; mt < 4; ++mt)
      af[mt] = *(const bf16x8*)(&As[p][wm + mt * 16 + l16][quad * 8]);
#pragma unroll
    for (int nt = 0; nt < 4; ++nt)
      bfr[nt] = *(const bf16x8*)(&Bs[p][wn + nt * 16 + l16][quad * 8]);
#pragma unroll
    for (int mt = 0; mt < 4; ++mt)
#pragma unroll
      for (int nt = 0; nt < 4; ++nt)
        acc[mt][nt] = mfma16(af[mt], bfr[nt], acc[mt][nt]);
    if (k0 + 64 < 1024) {  // stage t+1 done; t+2 still in flight
      asm volatile("s_waitcnt vmcnt(4)" ::: "memory");
    } else {
      asm volatile("s_waitcnt vmcnt(0)" ::: "memory");
    }
    __builtin_amdgcn_sched_barrier(0);
    __builtin_amdgcn_s_barrier();
    __builtin_amdgcn_sched_barrier(0);
    p = (p == 2) ? 0 : p + 1;
  }

  const bool rope = (sel < 2);
#pragma unroll
  for (int mt = 0; mt < 4; ++mt) {
#pragma unroll
    for (int nt = 0; nt < 4; ++nt) {
#pragma unroll
      for (int r = 0; r < 4; ++r) {
        int row_g = mbase + wm + mt * 16 + quad * 4 + r;
        int col_g = nb + wn + nt * 16 + l16;
        float val = acc[mt][nt][r];
        if (rope) {  // interleaved RoPE; partner col = col^1 lives in lane^1
          float other = __shfl_xor(val, 1);
          int s = (((row_g & 2047) << 3) + (col_g >> 7)) & 2047;  // view-seq position
          int d = col_g & 127;
          float invf = __expf(-0.14391156f * (float)(d >> 1));  // ln(1e4)/64
          float ang = (float)s * invf;
          float sv, cv;
          __sincosf(ang, &sv, &cv);
          val = (d & 1) ? (val * cv + other * sv) : (val * cv - other * sv);
        }
        C[(size_t)row_g * 1024 + col_g] = f2bf(val);
      }
    }
  }
}

// Plain per-bh transpose: vT[bh][d][s] = v[bh][s][d].
__global__ __launch_bounds__(256) void transpose_v(const unsigned short* __restrict__ Vn,
                                                   unsigned short* __restrict__ VT) {
  __shared__ __align__(16) unsigned short tile[64][72];
  const int t = threadIdx.x;
  const int s0 = blockIdx.x * 64;
  const int d0 = blockIdx.y * 64;
  const int bh = blockIdx.z;
  const size_t base = (size_t)bh * (2048 * 128);
#pragma unroll
  for (int i = 0; i < 2; ++i) {
    int c = t + (i << 8);
    int sr = c >> 3;
    int dc = (c & 7) << 3;
    *(uint4*)(&tile[sr][dc]) = *(const uint4*)(Vn + base + (size_t)(s0 + sr) * 128 + d0 + dc);
  }
  __syncthreads();
#pragma unroll
  for (int i = 0; i < 2; ++i) {
    int c = t + (i << 8);
    int dr = c >> 3;
    int sc = (c & 7) << 3;
    __align__(16) unsigned short tmp[8];
#pragma unroll
    for (int j = 0; j < 8; ++j) tmp[j] = tile[sc + j][dr];
    *(uint4*)(VT + base + (size_t)(d0 + dr) * 2048 + s0 + sc) = *(uint4*)tmp;
  }
}

// Final projection: A rows remap RowLinear pre-shuffle onto oT[bh][d][s];
// 3-buffer LDS pipeline, counted vmcnt, hoisted addresses (as gemm_qkv).
// Per-buffer layout (8192 elems): As rows[0,64) at [0,2048), As rows[64,128)
// at [2048,4096), Bs rows[0,64) at [4096,6144), Bs rows[64,128) at [6144,8192).
__global__ __launch_bounds__(256) void gemm_out(const unsigned short* __restrict__ OT,
                                                const unsigned short* __restrict__ Bt,
                                                float* __restrict__ C) {
  __shared__ __align__(16) char smem_raw[49152];  // 3 x (A 8KB + B 8KB); Ts 34816 B
  const int t = threadIdx.x;
  const int lane = t & 63;
  const int wid = t >> 6;
  const int quad = lane >> 4;
  const int l16 = lane & 15;
  const int wm = (wid >> 1) << 6;
  const int wn = (wid & 1) << 6;
  const int mbase = blockIdx.y * 128;
  const int nbase = blockIdx.x * 128;

  // per-thread loop-invariant staging addresses
  const unsigned short* aSrcs[2];
  const unsigned short* bSrcs[2];
#pragma unroll
  for (int i = 0; i < 2; ++i) {
    int c = t + (i << 8);
    int row = c >> 2;
    int col = (c & 3) << 3;
    int R = mbase + row;
    int b = R >> 11;
    int ii = R & 2047;
    aSrcs[i] = OT + (size_t)(b * 8 + (ii >> 8)) * (128 * 2048) +
               (size_t)((ii >> 1) & 127) * 2048 + ((ii & 1) << 10) + col;
    bSrcs[i] = Bt + (size_t)(nbase + row) * 1024 + col;
  }
  unsigned short* smE = (unsigned short*)smem_raw;

  auto stage = [&](int k0, int p) {
    const int po = p * 8192;  // elems per buffer (16384 B)
    gload_lds16(aSrcs[0] + k0, smE + po + t * 8);           // As elem  c0*8
    gload_lds16(aSrcs[1] + k0, smE + po + 2048 + t * 8);    // As elem  c1*8
    gload_lds16(bSrcs[0] + k0, smE + po + 4096 + t * 8);    // Bs elem  c0*8
    gload_lds16(bSrcs[1] + k0, smE + po + 6144 + t * 8);    // Bs elem  c1*8
  };

  f32x4 acc[4][4] = {};

  stage(0, 0);
  stage(32, 1);
  asm volatile("s_waitcnt vmcnt(4)" ::: "memory");
  __builtin_amdgcn_sched_barrier(0);
  __builtin_amdgcn_s_barrier();
  __builtin_amdgcn_sched_barrier(0);

  int p = 0;
  for (int k0 = 0; k0 < 1024; k0 += 32) {
    if (k0 + 64 < 1024) stage(k0 + 64, p == 0 ? 2 : p - 1);
    auto As = (unsigned short(*)[32])(smem_raw + p * 16384);
    auto Bs = (unsigned short(*)[32])(smem_raw + p * 16384 + 8192);
    bf16x8 af[4], bfr[4];
#pragma unroll
    for (int mt = 0; mt < 4; ++mt)
      af[mt] = *(const bf16x8*)(&As[wm + mt * 16 + l16][quad * 8]);
#pragma unroll
    for (int nt = 0; nt < 4; ++nt)
      bfr[nt] = *(const bf16x8*)(&Bs[wn + nt * 16 + l16][quad * 8]);
#pragma unroll
    for (int mt = 0; mt < 4; ++mt)
#pragma unroll
      for (int nt = 0; nt < 4; ++nt)
        acc[mt][nt] = mfma16(af[mt], bfr[nt], acc[mt][nt]);
    if (k0 + 64 < 1024) {
      asm volatile("s_waitcnt vmcnt(4)" ::: "memory");
    } else {
      asm volatile("s_waitcnt vmcnt(0)" ::: "memory");
    }
    __builtin_amdgcn_sched_barrier(0);
    __builtin_amdgcn_s_barrier();
    __builtin_amdgcn_sched_barrier(0);
    p = (p == 2) ? 0 : p + 1;
  }

  // out[b][s2][e2], s2 = (row&1)*1024 + col, e2 = (row&2047)>>1.
  float(*Ts)[68] = (float(*)[68])smem_raw;
  const int b = mbase >> 11;
  const int ebase = (mbase & 2047) >> 1;
#pragma unroll
  for (int p2 = 0; p2 < 2; ++p2) {
    __syncthreads();
#pragma unroll
    for (int mt = 0; mt < 4; ++mt)
#pragma unroll
      for (int nt = 0; nt < 4; ++nt)
#pragma unroll
        for (int rr = p2; rr < 4; rr += 2) {
          int col_local = wn + nt * 16 + l16;
          int row_local = wm + mt * 16 + quad * 4 + rr;
          Ts[col_local][row_local >> 1] = acc[mt][nt][rr];
        }
    __syncthreads();
    int srow = t >> 1;
    int e0 = (t & 1) << 5;
    float* dst = C + (size_t)b * 2097152 +
                 (size_t)(p2 * 1024 + nbase + srow) * 1024 + ebase + e0;
#pragma unroll
    for (int j = 0; j < 8; ++j)
      ((float4*)dst)[j] = *(const float4*)&Ts[srow][e0 + j * 4];
  }
}

// Flash attention [BH=32, S=2048, D=128]; full KV per block, BQ=128
// (4 waves x 32 q-cols), BKV=64. Swapped QK^T on 32x32 MFMA (S^T in regs,
// q = lane&31), in-register softmax, cvt_pk+permlane32 P-repack, PV as
// V^T x P^T -> O^T. K AND V double-buffered (64KB LDS), staged via
// global_load_lds with pre-swizzled source: issue tile t+1 at top of tile t,
// drain + ONE raw barrier after compute. Grid 512 = exactly 2 blocks/CU.
__global__ __launch_bounds__(256, 2) void flash_attn(const unsigned short* __restrict__ Q,
                                                     const unsigned short* __restrict__ Kg,
                                                     const unsigned short* __restrict__ VTg,
                                                     unsigned short* __restrict__ OT) {
  __shared__ __align__(16) char sm[65536];  // K0|K1|V0|V1 16KB each; epilogue overlays
  const int t = threadIdx.x;
  const int lane = t & 63;
  const int wid = t >> 6;
  const int l31 = lane & 31;
  const int hi = lane >> 5;
  const int x16 = (l31 & 7) << 4;  // XOR swizzle key (byte units)
  const int i = blockIdx.x;        // [0,512); XCD-aware swizzle
  const int bh = (i & 7) + ((i >> 3) & 3) * 8;
  const int qbase = (i >> 5) << 7;
  const size_t base = (size_t)bh * (2048 * 128);
  const float scale = 0.3535533905932738f;  // 1/sqrt(H=8)

  const unsigned short* Kg_b = Kg + base;
  const unsigned short* Vg_b = VTg + base;

  auto issueKV = [&](int kvoff, int pbit) {
    unsigned short* Kl = (unsigned short*)(sm + (pbit << 14));
    unsigned short* Vl = (unsigned short*)(sm + 32768 + (pbit << 14));
#pragma unroll
    for (int j = 0; j < 4; ++j) {
      int c = t + (j << 8);
      int row = c >> 4, ch = c & 15;
      gload_lds16(Kg_b + (size_t)(kvoff + row) * 128 + ((ch ^ (row & 7)) << 3),
                  Kl + c * 8);
      int d = c >> 3, cv = c & 7;
      gload_lds16(Vg_b + (size_t)d * 2048 + kvoff + ((cv ^ (d & 7)) << 3), Vl + c * 8);
    }
  };

  // Q fragments (B-operand): j = q = l31, k-dim slice = hi*8 within each 16.
  bf16x8 qf[8];
  {
    const unsigned short* qp = Q + base + (size_t)(qbase + wid * 32 + l31) * 128 + hi * 8;
#pragma unroll
    for (int ks = 0; ks < 8; ++ks) qf[ks] = *(const bf16x8*)(qp + ks * 16);
  }

  f32x16 accO[4] = {};  // O^T: rows d, cols q = l31
  float m = -__builtin_inff();
  float l = 0.f;

  issueKV(0, 0);
  drain_barrier();

  for (int kv = 0; kv < 2048; kv += 64) {
    const int p = (kv >> 6) & 1;
    if (kv + 64 < 2048) issueKV(kv + 64, p ^ 1);  // prefetch next tile (hidden)
    const char* Kb = sm + (p << 14);
    const char* Vb = sm + 32768 + (p << 14);

    // QK^T swapped: S^T (rows k, cols q = l31)
    f32x16 s0 = {}, s1 = {};
#pragma unroll
    for (int ks = 0; ks < 8; ++ks) {
      int cb = (ks * 32 + hi * 16) ^ x16;
      bf16x8 k0 = *(const bf16x8*)(Kb + l31 * 256 + cb);
      bf16x8 k1 = *(const bf16x8*)(Kb + 8192 + l31 * 256 + cb);
      s0 = mfma32(k0, qf[ks], s0);
      s1 = mfma32(k1, qf[ks], s1);
    }

    // online softmax: per-lane row (q = l31); 8-temp folded trees
    float t8[8];
#pragma unroll
    for (int r = 0; r < 8; ++r)
      t8[r] = fmaxf(fmaxf(s0[r], s0[r + 8]), fmaxf(s1[r], s1[r + 8]));
#pragma unroll
    for (int d = 4; d > 0; d >>= 1)
#pragma unroll
      for (int r = 0; r < d; ++r) t8[r] = fmaxf(t8[r], t8[r + d]);
    float mx = fmaxf(t8[0], __shfl_xor(t8[0], 32));
    if (__any(mx > m + 16.f)) {  // defer-max: P bounded by e^(16*scale)=287
      float mnew = fmaxf(m, mx);
      float alpha = __expf((m - mnew) * scale);
      l *= alpha;
#pragma unroll
      for (int dt = 0; dt < 4; ++dt)
#pragma unroll
        for (int r = 0; r < 16; ++r) accO[dt][r] *= alpha;
      m = mnew;
    }
    float negms = -m * scale;
#pragma unroll
    for (int r = 0; r < 16; ++r) s0[r] = __expf(fmaf(s0[r], scale, negms));
#pragma unroll
    for (int r = 0; r < 16; ++r) s1[r] = __expf(fmaf(s1[r], scale, negms));
#pragma unroll
    for (int r = 0; r < 8; ++r)
      t8[r] = (s0[r] + s0[r + 8]) + (s1[r] + s1[r + 8]);
#pragma unroll
    for (int d = 4; d > 0; d >>= 1)
#pragma unroll
      for (int r = 0; r < d; ++r) t8[r] += t8[r + d];
    l += t8[0] + __shfl_xor(t8[0], 32);

    // repack P^T -> B-fragments: cvt_pk pairs + permlane32_swap
    bf16x8 pfrag[4];
#pragma unroll
    for (int kb = 0; kb < 4; ++kb) {
      const f32x16& S = (kb < 2) ? s0 : s1;
      const int b = (kb & 1) * 8;
      unsigned int a0 = cvtpk_bf16(S[b + 0], S[b + 1]);
      unsigned int a1 = cvtpk_bf16(S[b + 2], S[b + 3]);
      unsigned int a2 = cvtpk_bf16(S[b + 4], S[b + 5]);
      unsigned int a3 = cvtpk_bf16(S[b + 6], S[b + 7]);
      pl32swap(a0, a2);
      pl32swap(a1, a3);
      union { unsigned int u[4]; bf16x8 v; } pu;
      pu.u[0] = a0; pu.u[1] = a1; pu.u[2] = a2; pu.u[3] = a3;
      pfrag[kb] = pu.v;
    }

    // PV: O^T[d][q] += V^T-frag (i=d) x P^T-frag (j=q)
#pragma unroll
    for (int dt = 0; dt < 4; ++dt) {
#pragma unroll
      for (int kb = 0; kb < 4; ++kb) {
        bf16x8 vfr = *(const bf16x8*)(Vb + l31 * 128 + dt * 4096 +
                                      ((kb * 32 + hi * 16) ^ x16));
        accO[dt] = mfma32(vfr, pfrag[kb], accO[dt]);
      }
    }

    // my prefetch DMAs landed long ago (hidden under compute); after this
    // barrier every wave's DMAs for tile t+1 are complete.
    drain_barrier();
  }

  // epilogue: accO is already O^T; normalize and stage to LDS for coalesced store
  auto To = (unsigned short(*)[136])sm;
  const float invl = 1.f / l;
  const int qloc = wid * 32 + l31;
#pragma unroll
  for (int dt = 0; dt < 4; ++dt)
#pragma unroll
    for (int r = 0; r < 16; ++r) {
      int d = dt * 32 + (r & 3) + ((r >> 2) << 3) + hi * 4;
      To[d][qloc] = f2bf(accO[dt][r] * invl);
    }
  __syncthreads();
  int dr = t >> 1;
  int off = (t & 1) << 6;
  unsigned short* dst = OT + base + (size_t)dr * 2048 + qbase + off;
#pragma unroll
  for (int j = 0; j < 8; ++j)
    ((uint4*)dst)[j] = *(const uint4*)&To[dr][off + j * 8];
}

extern "C" void kernel_launch(void* const* d_in, const int* in_sizes, int n_in,
                              void* d_out, int out_size, void* d_ws, size_t ws_size,
                              hipStream_t stream) {
  const float* emb = (const float*)d_in[0];
  const float* W1  = (const float*)d_in[1];
  const float* W2  = (const float*)d_in[2];
  const float* W3  = (const float*)d_in[3];
  const float* Wo  = (const float*)d_in[4];
  float* out = (float*)d_out;

  const size_t NELEM = (size_t)8 * 1024 * 1024;  // bf16 elems per [B*S, P] buffer
  unsigned short* q     = (unsigned short*)d_ws;   // [0,16) MB
  unsigned short* k     = q + NELEM;               // [16,32)
  unsigned short* vn    = k + NELEM;               // [32,48); later oT
  unsigned short* X     = vn + NELEM;              // [48,64): W123B -> vT -> WoB
  unsigned short* oT    = vn;
  unsigned short* vT    = X;
  unsigned short* W123B = X;                       // 6 MB, dead before vT written
  unsigned short* WoB   = X;                       // 2 MB, written after flash
  unsigned short* embB  = (unsigned short*)d_out;  // 16 MB bf16 scratch in the 32 MB
                                                   // fp32 out buffer; overwritten by gemm_out

  dim3 blk(256, 1, 1);
  convert_w3<<<dim3(1536), blk, 0, stream>>>(W1, W2, W3, W123B);
  convert_gen<<<dim3(4096), blk, 0, stream>>>(emb, embB);
  gemm_qkv<<<dim3(24, 64), blk, 0, stream>>>(embB, W123B, q, k, vn);
  transpose_v<<<dim3(32, 2, 32), blk, 0, stream>>>(vn, vT);
  flash_attn<<<dim3(512, 1, 1), blk, 0, stream>>>(q, k, vT, oT);
  convert_gen<<<dim3(512), blk, 0, stream>>>(Wo, WoB);
  gemm_out<<<dim3(8, 64), blk, 0, stream>>>(oT, WoB, out);
}

// Round 7
// 314.832 us; speedup vs baseline: 1.0130x; 1.0130x over previous
//
#include <hip/hip_runtime.h>

typedef float f32x4 __attribute__((ext_vector_type(4)));
typedef float f32x16 __attribute__((ext_vector_type(16)));
typedef __bf16 bf16x8 __attribute__((ext_vector_type(8)));

__device__ __forceinline__ unsigned short f2bf(float f) {
  unsigned int u = __float_as_uint(f);
  u = (u + 0x7FFFu + ((u >> 16) & 1u)) >> 16;
  return (unsigned short)u;
}
__device__ __forceinline__ float bf2f(unsigned short u) {
  return __uint_as_float((unsigned int)u << 16);
}

__device__ __forceinline__ f32x4 mfma16(bf16x8 a, bf16x8 b, f32x4 c) {
  return __builtin_amdgcn_mfma_f32_16x16x32_bf16(a, b, c, 0, 0, 0);
}
__device__ __forceinline__ f32x16 mfma32(bf16x8 a, bf16x8 b, f32x16 c) {
  return __builtin_amdgcn_mfma_f32_32x32x16_bf16(a, b, c, 0, 0, 0);
}

// packed f32->bf16 pair (RNE), lo = a, hi = b
__device__ __forceinline__ unsigned int cvtpk_bf16(float a, float b) {
  unsigned int r;
  asm("v_cvt_pk_bf16_f32 %0, %1, %2" : "=v"(r) : "v"(a), "v"(b));
  return r;
}
// swap upper 32 lanes of a with lower 32 lanes of b (both outputs used)
__device__ __forceinline__ void pl32swap(unsigned int& a, unsigned int& b) {
  asm("v_permlane32_swap_b32 %0, %1" : "+v"(a), "+v"(b));
}

__device__ __forceinline__ void load8_bf16(const unsigned short* p, unsigned short* d) {
  *(uint4*)d = *(const uint4*)p;
}
__device__ __forceinline__ void load8_bf16(const float* p, unsigned short* d) {
  float4 a = *(const float4*)p;
  float4 b = *(const float4*)(p + 4);
  __align__(16) unsigned short t[8] = {f2bf(a.x), f2bf(a.y), f2bf(a.z), f2bf(a.w),
                                       f2bf(b.x), f2bf(b.y), f2bf(b.z), f2bf(b.w)};
  *(uint4*)d = *(uint4*)t;
}

// Async global->LDS 16B DMA. LDS dest must be wave-uniform base + lane*16.
__device__ __forceinline__ void gload_lds16(const unsigned short* g, unsigned short* l) {
  __builtin_amdgcn_global_load_lds(
      (const __attribute__((address_space(1))) void*)g,
      (__attribute__((address_space(3))) void*)l, 16, 0, 0);
}

__device__ __forceinline__ void drain_barrier() {
  asm volatile("s_waitcnt vmcnt(0)" ::: "memory");
  __builtin_amdgcn_sched_barrier(0);
  __builtin_amdgcn_s_barrier();
  __builtin_amdgcn_sched_barrier(0);
}

__device__ __forceinline__ void wait2_barrier() {
  asm volatile("s_waitcnt vmcnt(2)" ::: "memory");
  __builtin_amdgcn_sched_barrier(0);
  __builtin_amdgcn_s_barrier();
  __builtin_amdgcn_sched_barrier(0);
}

// fp32 -> bf16, 8 elems/thread.
__global__ __launch_bounds__(256) void convert_gen(const float* __restrict__ src,
                                                   unsigned short* __restrict__ dst) {
  int idx = (blockIdx.x * 256 + threadIdx.x) * 8;
  __align__(16) unsigned short t[8];
  load8_bf16(src + idx, t);
  *(uint4*)(dst + idx) = *(uint4*)t;
}

// W1|W2|W3 -> bf16 in MFMA-fragment-linear order:
// idx16 = (((nb*32+ks)*2+wn)*4+nt)*64 + lane, lane = quad*16 + l16, where
// p = nb*128+wn*64+nt*16+l16 (W row), k = ks*32+quad*8+e. 1536 blocks.
__global__ __launch_bounds__(256) void convert_w3(const float* __restrict__ W1,
                                                  const float* __restrict__ W2,
                                                  const float* __restrict__ W3,
                                                  unsigned short* __restrict__ dst) {
  int i = blockIdx.x;
  int sel = i >> 9;
  const float* src = (sel == 0) ? W1 : (sel == 1) ? W2 : W3;
  int w = i & 511;
  int t = threadIdx.x;
  int p = 2 * w + (t >> 7);
  int kc = t & 127;  // 16B chunk index along K
  __align__(16) unsigned short tmp[8];
  load8_bf16(src + (size_t)p * 1024 + kc * 8, tmp);
  int lane = (kc & 3) * 16 + (p & 15);
  size_t idx16 = ((((size_t)(p >> 7) * 32 + (kc >> 2)) * 2 + ((p >> 6) & 1)) * 4 +
                  ((p >> 4) & 3)) * 64 + lane;
  *(uint4*)(dst + (size_t)sel * 1048576 + idx16 * 8) = *(uint4*)tmp;
}

// Wo -> bf16 fragment-linear (same mapping, single matrix). 512 blocks.
__global__ __launch_bounds__(256) void convert_wo(const float* __restrict__ Wo,
                                                  unsigned short* __restrict__ dst) {
  int w = blockIdx.x;
  int t = threadIdx.x;
  int p = 2 * w + (t >> 7);
  int kc = t & 127;
  __align__(16) unsigned short tmp[8];
  load8_bf16(Wo + (size_t)p * 1024 + kc * 8, tmp);
  int lane = (kc & 3) * 16 + (p & 15);
  size_t idx16 = ((((size_t)(p >> 7) * 32 + (kc >> 2)) * 2 + ((p >> 6) & 1)) * 4 +
                  ((p >> 4) & 3)) * 64 + lane;
  *(uint4*)(dst + idx16 * 8) = *(uint4*)tmp;
}

// Fused QKV projection. A staged in LDS (3-buffer, 2-deep DMA prefetch, counted
// vmcnt); B read DIRECT from global in fragment-linear order (L2-hot, coalesced
// 1KB/wave-instr) -- no B LDS traffic at all (halves the LDS-pipe load that
// capped this kernel at ~106us across three different pipeline schedules).
__global__ __launch_bounds__(256) void gemm_qkv(const unsigned short* __restrict__ A,
                                                const unsigned short* __restrict__ WBf,
                                                unsigned short* __restrict__ q,
                                                unsigned short* __restrict__ k,
                                                unsigned short* __restrict__ v) {
  __shared__ __align__(16) unsigned short As[3][128][32];  // 24 KB
  const int t = threadIdx.x;
  const int lane = t & 63;
  const int wid = t >> 6;
  const int quad = lane >> 4;
  const int l16 = lane & 15;
  const int wm = (wid >> 1) << 6;
  const int wn = (wid & 1) << 6;
  const int sel = blockIdx.x >> 3;
  const int nb = blockIdx.x & 7;
  const int mbase = blockIdx.y * 128;
  unsigned short* C = (sel == 0) ? q : (sel == 1) ? k : v;

  // A staging: 2 x 16B chunks/thread, lane-linear LDS dest
  const unsigned short* aSrc0 = A + (size_t)(mbase + (t >> 2)) * 1024 + ((t & 3) << 3);
  const unsigned short* aSrc1 = A + (size_t)(mbase + 64 + (t >> 2)) * 1024 + ((t & 3) << 3);
  unsigned short* aDst0 = &As[0][0][0] + t * 8;
  unsigned short* aDst1 = &As[0][0][0] + 2048 + t * 8;
  auto stageA = [&](int k0, int p) {
    gload_lds16(aSrc0 + k0, aDst0 + p * 4096);
    gload_lds16(aSrc1 + k0, aDst1 + p * 4096);
  };

  // B fragment pointer: this wave's (nb, wn) panel; +512 elems per nt,
  // +4096 elems per K-step.
  const unsigned short* pB = WBf + (size_t)sel * 1048576 +
                             ((size_t)(nb * 64 + (wid & 1)) * 4) * 512 + lane * 8;

  f32x4 acc[4][4] = {};

  stageA(0, 0);
  stageA(32, 1);
  asm volatile("s_waitcnt vmcnt(2)" ::: "memory");  // A(0) landed, A(1) in flight
  __builtin_amdgcn_sched_barrier(0);
  __builtin_amdgcn_s_barrier();
  __builtin_amdgcn_sched_barrier(0);

  int p = 0;
  for (int k0 = 0; k0 < 1024; k0 += 32) {
    bf16x8 bfr[4];
#pragma unroll
    for (int nt = 0; nt < 4; ++nt) bfr[nt] = *(const bf16x8*)(pB + nt * 512);
    pB += 4096;
    if (k0 + 64 < 1024) stageA(k0 + 64, p == 0 ? 2 : p - 1);
    bf16x8 af[4];
#pragma unroll
    for (int mt = 0; mt < 4; ++mt)
      af[mt] = *(const bf16x8*)(&As[p][wm + mt * 16 + l16][quad * 8]);
    // nt-outer: first MFMAs need only bfr[0] -> compute starts as B lands
#pragma unroll
    for (int nt = 0; nt < 4; ++nt)
#pragma unroll
      for (int mt = 0; mt < 4; ++mt)
        acc[mt][nt] = mfma16(af[mt], bfr[nt], acc[mt][nt]);
    wait2_barrier();  // A(t+1) drained (oldest); A(t+2) stays in flight
    p = (p == 2) ? 0 : p + 1;
  }

  const bool rope = (sel < 2);
#pragma unroll
  for (int mt = 0; mt < 4; ++mt) {
#pragma unroll
    for (int nt = 0; nt < 4; ++nt) {
#pragma unroll
      for (int r = 0; r < 4; ++r) {
        int row_g = mbase + wm + mt * 16 + quad * 4 + r;
        int col_g = (nb << 7) + wn + nt * 16 + l16;
        float val = acc[mt][nt][r];
        if (rope) {  // interleaved RoPE; partner col = col^1 lives in lane^1
          float other = __shfl_xor(val, 1);
          int s = (((row_g & 2047) << 3) + (col_g >> 7)) & 2047;  // view-seq position
          int d = col_g & 127;
          float invf = __expf(-0.14391156f * (float)(d >> 1));  // ln(1e4)/64
          float ang = (float)s * invf;
          float sv, cv;
          __sincosf(ang, &sv, &cv);
          val = (d & 1) ? (val * cv + other * sv) : (val * cv - other * sv);
        }
        C[(size_t)row_g * 1024 + col_g] = f2bf(val);
      }
    }
  }
}

// Plain per-bh transpose: vT[bh][d][s] = v[bh][s][d].
__global__ __launch_bounds__(256) void transpose_v(const unsigned short* __restrict__ Vn,
                                                   unsigned short* __restrict__ VT) {
  __shared__ __align__(16) unsigned short tile[64][72];
  const int t = threadIdx.x;
  const int s0 = blockIdx.x * 64;
  const int d0 = blockIdx.y * 64;
  const int bh = blockIdx.z;
  const size_t base = (size_t)bh * (2048 * 128);
#pragma unroll
  for (int i = 0; i < 2; ++i) {
    int c = t + (i << 8);
    int sr = c >> 3;
    int dc = (c & 7) << 3;
    *(uint4*)(&tile[sr][dc]) = *(const uint4*)(Vn + base + (size_t)(s0 + sr) * 128 + d0 + dc);
  }
  __syncthreads();
#pragma unroll
  for (int i = 0; i < 2; ++i) {
    int c = t + (i << 8);
    int dr = c >> 3;
    int sc = (c & 7) << 3;
    __align__(16) unsigned short tmp[8];
#pragma unroll
    for (int j = 0; j < 8; ++j) tmp[j] = tile[sc + j][dr];
    *(uint4*)(VT + base + (size_t)(d0 + dr) * 2048 + s0 + sc) = *(uint4*)tmp;
  }
}

// Final projection: A rows remap RowLinear pre-shuffle onto oT[bh][d][s];
// A via LDS 3-buffer DMA pipeline, B (WoB) direct-from-global fragment-linear.
__global__ __launch_bounds__(256) void gemm_out(const unsigned short* __restrict__ OT,
                                                const unsigned short* __restrict__ Bf,
                                                float* __restrict__ C) {
  __shared__ __align__(16) char smem_raw[34816];  // 3 x 8KB As; Ts epilogue 34816 B
  const int t = threadIdx.x;
  const int lane = t & 63;
  const int wid = t >> 6;
  const int quad = lane >> 4;
  const int l16 = lane & 15;
  const int wm = (wid >> 1) << 6;
  const int wn = (wid & 1) << 6;
  const int mbase = blockIdx.y * 128;
  const int nbx = blockIdx.x;  // nbase = nbx*128

  // per-thread loop-invariant A staging addresses (RowLinear remap)
  const unsigned short* aSrcs[2];
#pragma unroll
  for (int i = 0; i < 2; ++i) {
    int c = t + (i << 8);
    int row = c >> 2;
    int col = (c & 3) << 3;
    int R = mbase + row;
    int b = R >> 11;
    int ii = R & 2047;
    aSrcs[i] = OT + (size_t)(b * 8 + (ii >> 8)) * (128 * 2048) +
               (size_t)((ii >> 1) & 127) * 2048 + ((ii & 1) << 10) + col;
  }
  unsigned short* smE = (unsigned short*)smem_raw;
  auto stageA = [&](int k0, int p) {
    gload_lds16(aSrcs[0] + k0, smE + p * 4096 + t * 8);
    gload_lds16(aSrcs[1] + k0, smE + p * 4096 + 2048 + t * 8);
  };

  const unsigned short* pB = Bf + ((size_t)(nbx * 64 + (wid & 1)) * 4) * 512 + lane * 8;

  f32x4 acc[4][4] = {};

  stageA(0, 0);
  stageA(32, 1);
  asm volatile("s_waitcnt vmcnt(2)" ::: "memory");
  __builtin_amdgcn_sched_barrier(0);
  __builtin_amdgcn_s_barrier();
  __builtin_amdgcn_sched_barrier(0);

  int p = 0;
  for (int k0 = 0; k0 < 1024; k0 += 32) {
    bf16x8 bfr[4];
#pragma unroll
    for (int nt = 0; nt < 4; ++nt) bfr[nt] = *(const bf16x8*)(pB + nt * 512);
    pB += 4096;
    if (k0 + 64 < 1024) stageA(k0 + 64, p == 0 ? 2 : p - 1);
    auto As = (unsigned short(*)[32])(smem_raw + p * 8192);
    bf16x8 af[4];
#pragma unroll
    for (int mt = 0; mt < 4; ++mt)
      af[mt] = *(const bf16x8*)(&As[wm + mt * 16 + l16][quad * 8]);
#pragma unroll
    for (int nt = 0; nt < 4; ++nt)
#pragma unroll
      for (int mt = 0; mt < 4; ++mt)
        acc[mt][nt] = mfma16(af[mt], bfr[nt], acc[mt][nt]);
    wait2_barrier();
    p = (p == 2) ? 0 : p + 1;
  }

  // out[b][s2][e2], s2 = (row&1)*1024 + col, e2 = (row&2047)>>1.
  float(*Ts)[68] = (float(*)[68])smem_raw;
  const int b = mbase >> 11;
  const int ebase = (mbase & 2047) >> 1;
#pragma unroll
  for (int p2 = 0; p2 < 2; ++p2) {
    __syncthreads();
#pragma unroll
    for (int mt = 0; mt < 4; ++mt)
#pragma unroll
      for (int nt = 0; nt < 4; ++nt)
#pragma unroll
        for (int rr = p2; rr < 4; rr += 2) {
          int col_local = wn + nt * 16 + l16;
          int row_local = wm + mt * 16 + quad * 4 + rr;
          Ts[col_local][row_local >> 1] = acc[mt][nt][rr];
        }
    __syncthreads();
    int srow = t >> 1;
    int e0 = (t & 1) << 5;
    float* dst = C + (size_t)b * 2097152 +
                 (size_t)(p2 * 1024 + nbx * 128 + srow) * 1024 + ebase + e0;
#pragma unroll
    for (int j = 0; j < 8; ++j)
      ((float4*)dst)[j] = *(const float4*)&Ts[srow][e0 + j * 4];
  }
}

// Flash attention [BH=32, S=2048, D=128]; full KV per block, BQ=128
// (4 waves x 32 q-cols), BKV=64. Swapped QK^T on 32x32 MFMA (S^T in regs,
// q = lane&31), in-register softmax, cvt_pk+permlane32 P-repack, PV as
// V^T x P^T -> O^T. K AND V double-buffered (64KB LDS), staged via
// global_load_lds with pre-swizzled source: issue tile t+1 at top of tile t,
// drain + ONE raw barrier after compute. Grid 512 = exactly 2 blocks/CU.
__global__ __launch_bounds__(256, 2) void flash_attn(const unsigned short* __restrict__ Q,
                                                     const unsigned short* __restrict__ Kg,
                                                     const unsigned short* __restrict__ VTg,
                                                     unsigned short* __restrict__ OT) {
  __shared__ __align__(16) char sm[65536];  // K0|K1|V0|V1 16KB each; epilogue overlays
  const int t = threadIdx.x;
  const int lane = t & 63;
  const int wid = t >> 6;
  const int l31 = lane & 31;
  const int hi = lane >> 5;
  const int x16 = (l31 & 7) << 4;  // XOR swizzle key (byte units)
  const int i = blockIdx.x;        // [0,512); XCD-aware swizzle
  const int bh = (i & 7) + ((i >> 3) & 3) * 8;
  const int qbase = (i >> 5) << 7;
  const size_t base = (size_t)bh * (2048 * 128);
  const float scale = 0.3535533905932738f;  // 1/sqrt(H=8)

  const unsigned short* Kg_b = Kg + base;
  const unsigned short* Vg_b = VTg + base;

  auto issueKV = [&](int kvoff, int pbit) {
    unsigned short* Kl = (unsigned short*)(sm + (pbit << 14));
    unsigned short* Vl = (unsigned short*)(sm + 32768 + (pbit << 14));
#pragma unroll
    for (int j = 0; j < 4; ++j) {
      int c = t + (j << 8);
      int row = c >> 4, ch = c & 15;
      gload_lds16(Kg_b + (size_t)(kvoff + row) * 128 + ((ch ^ (row & 7)) << 3),
                  Kl + c * 8);
      int d = c >> 3, cv = c & 7;
      gload_lds16(Vg_b + (size_t)d * 2048 + kvoff + ((cv ^ (d & 7)) << 3), Vl + c * 8);
    }
  };

  // Q fragments (B-operand): j = q = l31, k-dim slice = hi*8 within each 16.
  bf16x8 qf[8];
  {
    const unsigned short* qp = Q + base + (size_t)(qbase + wid * 32 + l31) * 128 + hi * 8;
#pragma unroll
    for (int ks = 0; ks < 8; ++ks) qf[ks] = *(const bf16x8*)(qp + ks * 16);
  }

  f32x16 accO[4] = {};  // O^T: rows d, cols q = l31
  float m = -__builtin_inff();
  float l = 0.f;

  issueKV(0, 0);
  drain_barrier();

  for (int kv = 0; kv < 2048; kv += 64) {
    const int p = (kv >> 6) & 1;
    if (kv + 64 < 2048) issueKV(kv + 64, p ^ 1);  // prefetch next tile (hidden)
    const char* Kb = sm + (p << 14);
    const char* Vb = sm + 32768 + (p << 14);

    // QK^T swapped: S^T (rows k, cols q = l31)
    f32x16 s0 = {}, s1 = {};
#pragma unroll
    for (int ks = 0; ks < 8; ++ks) {
      int cb = (ks * 32 + hi * 16) ^ x16;
      bf16x8 k0 = *(const bf16x8*)(Kb + l31 * 256 + cb);
      bf16x8 k1 = *(const bf16x8*)(Kb + 8192 + l31 * 256 + cb);
      s0 = mfma32(k0, qf[ks], s0);
      s1 = mfma32(k1, qf[ks], s1);
    }

    // online softmax: per-lane row (q = l31); 8-temp folded trees
    float t8[8];
#pragma unroll
    for (int r = 0; r < 8; ++r)
      t8[r] = fmaxf(fmaxf(s0[r], s0[r + 8]), fmaxf(s1[r], s1[r + 8]));
#pragma unroll
    for (int d = 4; d > 0; d >>= 1)
#pragma unroll
      for (int r = 0; r < d; ++r) t8[r] = fmaxf(t8[r], t8[r + d]);
    float mx = fmaxf(t8[0], __shfl_xor(t8[0], 32));
    if (__any(mx > m + 16.f)) {  // defer-max: P bounded by e^(16*scale)=287
      float mnew = fmaxf(m, mx);
      float alpha = __expf((m - mnew) * scale);
      l *= alpha;
#pragma unroll
      for (int dt = 0; dt < 4; ++dt)
#pragma unroll
        for (int r = 0; r < 16; ++r) accO[dt][r] *= alpha;
      m = mnew;
    }
    float negms = -m * scale;
#pragma unroll
    for (int r = 0; r < 16; ++r) s0[r] = __expf(fmaf(s0[r], scale, negms));
#pragma unroll
    for (int r = 0; r < 16; ++r) s1[r] = __expf(fmaf(s1[r], scale, negms));
#pragma unroll
    for (int r = 0; r < 8; ++r)
      t8[r] = (s0[r] + s0[r + 8]) + (s1[r] + s1[r + 8]);
#pragma unroll
    for (int d = 4; d > 0; d >>= 1)
#pragma unroll
      for (int r = 0; r < d; ++r) t8[r] += t8[r + d];
    l += t8[0] + __shfl_xor(t8[0], 32);

    // repack P^T -> B-fragments: cvt_pk pairs + permlane32_swap
    bf16x8 pfrag[4];
#pragma unroll
    for (int kb = 0; kb < 4; ++kb) {
      const f32x16& S = (kb < 2) ? s0 : s1;
      const int b = (kb & 1) * 8;
      unsigned int a0 = cvtpk_bf16(S[b + 0], S[b + 1]);
      unsigned int a1 = cvtpk_bf16(S[b + 2], S[b + 3]);
      unsigned int a2 = cvtpk_bf16(S[b + 4], S[b + 5]);
      unsigned int a3 = cvtpk_bf16(S[b + 6], S[b + 7]);
      pl32swap(a0, a2);
      pl32swap(a1, a3);
      union { unsigned int u[4]; bf16x8 v; } pu;
      pu.u[0] = a0; pu.u[1] = a1; pu.u[2] = a2; pu.u[3] = a3;
      pfrag[kb] = pu.v;
    }

    // PV: O^T[d][q] += V^T-frag (i=d) x P^T-frag (j=q)
#pragma unroll
    for (int dt = 0; dt < 4; ++dt) {
#pragma unroll
      for (int kb = 0; kb < 4; ++kb) {
        bf16x8 vfr = *(const bf16x8*)(Vb + l31 * 128 + dt * 4096 +
                                      ((kb * 32 + hi * 16) ^ x16));
        accO[dt] = mfma32(vfr, pfrag[kb], accO[dt]);
      }
    }

    // my prefetch DMAs landed long ago (hidden under compute); after this
    // barrier every wave's DMAs for tile t+1 are complete.
    drain_barrier();
  }

  // epilogue: accO is already O^T; normalize and stage to LDS for coalesced store
  auto To = (unsigned short(*)[136])sm;
  const float invl = 1.f / l;
  const int qloc = wid * 32 + l31;
#pragma unroll
  for (int dt = 0; dt < 4; ++dt)
#pragma unroll
    for (int r = 0; r < 16; ++r) {
      int d = dt * 32 + (r & 3) + ((r >> 2) << 3) + hi * 4;
      To[d][qloc] = f2bf(accO[dt][r] * invl);
    }
  __syncthreads();
  int dr = t >> 1;
  int off = (t & 1) << 6;
  unsigned short* dst = OT + base + (size_t)dr * 2048 + qbase + off;
#pragma unroll
  for (int j = 0; j < 8; ++j)
    ((uint4*)dst)[j] = *(const uint4*)&To[dr][off + j * 8];
}

extern "C" void kernel_launch(void* const* d_in, const int* in_sizes, int n_in,
                              void* d_out, int out_size, void* d_ws, size_t ws_size,
                              hipStream_t stream) {
  const float* emb = (const float*)d_in[0];
  const float* W1  = (const float*)d_in[1];
  const float* W2  = (const float*)d_in[2];
  const float* W3  = (const float*)d_in[3];
  const float* Wo  = (const float*)d_in[4];
  float* out = (float*)d_out;

  const size_t NELEM = (size_t)8 * 1024 * 1024;  // bf16 elems per [B*S, P] buffer
  unsigned short* q     = (unsigned short*)d_ws;   // [0,16) MB
  unsigned short* k     = q + NELEM;               // [16,32)
  unsigned short* vn    = k + NELEM;               // [32,48); later oT
  unsigned short* X     = vn + NELEM;              // [48,64): W123B -> vT -> WoB
  unsigned short* oT    = vn;
  unsigned short* vT    = X;
  unsigned short* W123B = X;                       // 6 MB, dead before vT written
  unsigned short* WoB   = X;                       // 2 MB, written after flash
  unsigned short* embB  = (unsigned short*)d_out;  // 16 MB bf16 scratch in the 32 MB
                                                   // fp32 out buffer; overwritten by gemm_out

  dim3 blk(256, 1, 1);
  convert_w3<<<dim3(1536), blk, 0, stream>>>(W1, W2, W3, W123B);
  convert_gen<<<dim3(4096), blk, 0, stream>>>(emb, embB);
  gemm_qkv<<<dim3(24, 64), blk, 0, stream>>>(embB, W123B, q, k, vn);
  transpose_v<<<dim3(32, 2, 32), blk, 0, stream>>>(vn, vT);
  flash_attn<<<dim3(512, 1, 1), blk, 0, stream>>>(q, k, vT, oT);
  convert_wo<<<dim3(512), blk, 0, stream>>>(Wo, WoB);
  gemm_out<<<dim3(8, 64), blk, 0, stream>>>(oT, WoB, out);
}